// Round 8
// baseline (298.701 us; speedup 1.0000x reference)
//
#include <hip/hip_runtime.h>
#include <cstddef>

#define B_      4
#define N_      1024
#define DIM_    512
#define H_      8
#define D_      64
#define INNER_  512
#define TRIPLE_ 1536
#define KK_     716        // int(1024 * 0.7)
#define SCALE_  0.125f     // 64^-0.5

typedef short bf16x8 __attribute__((ext_vector_type(8)));
typedef float f32x4  __attribute__((ext_vector_type(4)));
typedef unsigned short ushort_t;
typedef ushort_t us8 __attribute__((ext_vector_type(8)));

__device__ __forceinline__ unsigned short bf16_rne(float f) {
    unsigned u = __float_as_uint(f);
    return (unsigned short)((u + 0x7FFFu + ((u >> 16) & 1u)) >> 16);
}
__device__ __forceinline__ float bf16_f(unsigned short s) {
    return __uint_as_float((unsigned)s << 16);
}
// order-preserving float->uint key (descending float == descending uint)
__device__ __forceinline__ unsigned f2key(float f) {
    unsigned u = __float_as_uint(f);
    return u ^ ((u & 0x80000000u) ? 0xFFFFFFFFu : 0x80000000u);
}
__device__ __forceinline__ float key2f(unsigned k) {
    unsigned u = (k & 0x80000000u) ? (k ^ 0x80000000u) : ~k;
    return __uint_as_float(u);
}
// wave-wide count of per-lane tallies lc in [0,16] via 5 bit-plane ballots
__device__ __forceinline__ int wave_count(int lc) {
    int c = __popcll(__ballot(lc & 1));
    c += __popcll(__ballot(lc & 2)) << 1;
    c += __popcll(__ballot(lc & 4)) << 2;
    c += __popcll(__ballot(lc & 8)) << 3;
    c += __popcll(__ballot(lc & 16)) << 4;
    return c;
}
// load 8 contiguous f32, emit hi/lo bf16 fragments
__device__ __forceinline__ void split8(const float* __restrict__ src,
                                       bf16x8& h8, bf16x8& l8) {
    float4 a = *(const float4*)src;
    float4 b = *(const float4*)(src + 4);
    float v[8] = {a.x, a.y, a.z, a.w, b.x, b.y, b.z, b.w};
#pragma unroll
    for (int i = 0; i < 8; ++i) {
        ushort_t hb = bf16_rne(v[i]);
        h8[i] = (short)hb;
        l8[i] = (short)bf16_rne(v[i] - bf16_f(hb));
    }
}

// ---------------------------------------------------------------------------
// Fused weight transpose+split: blocks [0,48) -> w_qkv, [48,64) -> w_out.
// ---------------------------------------------------------------------------
__global__ __launch_bounds__(256) void conv_wT2(const float* __restrict__ Wq,
                                                const float* __restrict__ Wo,
                                                ushort_t* __restrict__ WqTh,
                                                ushort_t* __restrict__ WqTl,
                                                ushort_t* __restrict__ WoTh,
                                                ushort_t* __restrict__ WoTl) {
    __shared__ float tile[32][33];
    const bool isQ = blockIdx.x < 48;
    const int  nb  = (isQ ? blockIdx.x : blockIdx.x - 48) * 32;
    const int  kb  = blockIdx.y * 32;
    const int  Nn  = isQ ? TRIPLE_ : DIM_;
    const float* W = isQ ? Wq : Wo;
    ushort_t* Th   = isQ ? WqTh : WoTh;
    ushort_t* Tl   = isQ ? WqTl : WoTl;
    const int tx = threadIdx.x & 31, ty = threadIdx.x >> 5;   // ty 0..7
    for (int yy = ty; yy < 32; yy += 8)
        tile[yy][tx] = W[(size_t)(kb + yy) * Nn + nb + tx];
    __syncthreads();
    for (int yy = ty; yy < 32; yy += 8) {
        float v = tile[tx][yy];
        ushort_t hb = bf16_rne(v);
        size_t idx = (size_t)(nb + yy) * DIM_ + kb + tx;
        Th[idx] = hb;
        Tl[idx] = bf16_rne(v - bf16_f(hb));
    }
}

// ---------------------------------------------------------------------------
// Split-bf16 MFMA GEMM core (bf16 A inputs): wave = 32x64, WG = 4 waves.
// ---------------------------------------------------------------------------
#define GEMM_CORE(K_DIM, AH, AL, BH, BL)                                     \
    const int t = threadIdx.x, w = t >> 6, l = t & 63;                       \
    const int ln = l & 15, quad = l >> 4;                                    \
    const int n0 = blockIdx.y * 64;                                          \
    const int m0 = blockIdx.x * 128 + w * 32;                                \
    f32x4 acc[2][4] = {};                                                    \
    {                                                                        \
        const size_t arow0 = (size_t)(m0 + ln) * (K_DIM);                    \
        const size_t arow1 = (size_t)(m0 + 16 + ln) * (K_DIM);               \
        for (int k0 = 0; k0 < (K_DIM); k0 += 32) {                           \
            const int ko = k0 + quad * 8;                                    \
            bf16x8 ah0 = *(const bf16x8*)&AH[arow0 + ko];                    \
            bf16x8 al0 = *(const bf16x8*)&AL[arow0 + ko];                    \
            bf16x8 ah1 = *(const bf16x8*)&AH[arow1 + ko];                    \
            bf16x8 al1 = *(const bf16x8*)&AL[arow1 + ko];                    \
            _Pragma("unroll")                                                \
            for (int j = 0; j < 4; ++j) {                                    \
                const size_t brow = (size_t)(n0 + j * 16 + ln) * (K_DIM) + ko; \
                bf16x8 bh = *(const bf16x8*)&BH[brow];                       \
                bf16x8 bl = *(const bf16x8*)&BL[brow];                       \
                acc[0][j] = __builtin_amdgcn_mfma_f32_16x16x32_bf16(ah0, bh, acc[0][j], 0, 0, 0); \
                acc[0][j] = __builtin_amdgcn_mfma_f32_16x16x32_bf16(al0, bh, acc[0][j], 0, 0, 0); \
                acc[0][j] = __builtin_amdgcn_mfma_f32_16x16x32_bf16(ah0, bl, acc[0][j], 0, 0, 0); \
                acc[1][j] = __builtin_amdgcn_mfma_f32_16x16x32_bf16(ah1, bh, acc[1][j], 0, 0, 0); \
                acc[1][j] = __builtin_amdgcn_mfma_f32_16x16x32_bf16(al1, bh, acc[1][j], 0, 0, 0); \
                acc[1][j] = __builtin_amdgcn_mfma_f32_16x16x32_bf16(ah1, bl, acc[1][j], 0, 0, 0); \
            }                                                                \
        }                                                                    \
    }

// qkv GEMM: reads x fp32 directly, splits A frags in-register.
__global__ __launch_bounds__(256) void gemm_qkv_mfma(
    const float* __restrict__ X,
    const ushort_t* __restrict__ Wh, const ushort_t* __restrict__ Wl,
    ushort_t* __restrict__ Qh, ushort_t* __restrict__ Ql,
    ushort_t* __restrict__ Kh, ushort_t* __restrict__ Kl,
    ushort_t* __restrict__ Vt) {
    __shared__ ushort_t stile[4][4608];   // 36 KB, per-wave scratch
    const int t = threadIdx.x, w = t >> 6, l = t & 63;
    const int ln = l & 15, quad = l >> 4;
    const int n0 = blockIdx.y * 64;
    const int m0 = blockIdx.x * 128 + w * 32;
    f32x4 acc[2][4] = {};
    {
        const size_t xrow0 = (size_t)(m0 + ln) * DIM_;
        const size_t xrow1 = (size_t)(m0 + 16 + ln) * DIM_;
        for (int k0 = 0; k0 < DIM_; k0 += 32) {
            const int ko = k0 + quad * 8;
            bf16x8 ah0, al0, ah1, al1;
            split8(&X[xrow0 + ko], ah0, al0);
            split8(&X[xrow1 + ko], ah1, al1);
#pragma unroll
            for (int j = 0; j < 4; ++j) {
                const size_t brow = (size_t)(n0 + j * 16 + ln) * DIM_ + ko;
                bf16x8 bh = *(const bf16x8*)&Wh[brow];
                bf16x8 bl = *(const bf16x8*)&Wl[brow];
                acc[0][j] = __builtin_amdgcn_mfma_f32_16x16x32_bf16(ah0, bh, acc[0][j], 0, 0, 0);
                acc[0][j] = __builtin_amdgcn_mfma_f32_16x16x32_bf16(al0, bh, acc[0][j], 0, 0, 0);
                acc[0][j] = __builtin_amdgcn_mfma_f32_16x16x32_bf16(ah0, bl, acc[0][j], 0, 0, 0);
                acc[1][j] = __builtin_amdgcn_mfma_f32_16x16x32_bf16(ah1, bh, acc[1][j], 0, 0, 0);
                acc[1][j] = __builtin_amdgcn_mfma_f32_16x16x32_bf16(al1, bh, acc[1][j], 0, 0, 0);
                acc[1][j] = __builtin_amdgcn_mfma_f32_16x16x32_bf16(ah1, bl, acc[1][j], 0, 0, 0);
            }
        }
    }
    const int sec = n0 >> 9;           // block-uniform
    const int h   = (n0 >> 6) & 7;
    ushort_t* tw  = stile[w];
    const int b = m0 >> 10, nnb = m0 & 1023;
    if (sec < 2) {
        ushort_t* Hp = sec ? Kh : Qh;
        ushort_t* Lp = sec ? Kl : Ql;
#pragma unroll
        for (int i = 0; i < 2; ++i)
#pragma unroll
            for (int j = 0; j < 4; ++j)
#pragma unroll
                for (int g = 0; g < 4; ++g) {
                    const float v = acc[i][j][g];
                    const ushort_t hb = bf16_rne(v);
                    const ushort_t lb = bf16_rne(v - bf16_f(hb));
                    const int tok = i * 16 + quad * 4 + g;
                    const int d   = j * 16 + ln;
                    tw[tok * 72 + d]        = hb;
                    tw[2304 + tok * 72 + d] = lb;
                }
        __syncthreads();
        const size_t rowbase = ((size_t)(b * 8 + h) * 1024 + nnb) * 64;
        const int dd = (l & 7) * 8;
#pragma unroll
        for (int s = 0; s < 4; ++s) {
            const int tl = s * 8 + (l >> 3);
            const size_t off = rowbase + (size_t)tl * 64 + dd;
            *(us8*)&Hp[off] = *(const us8*)&tw[tl * 72 + dd];
            *(us8*)&Lp[off] = *(const us8*)&tw[2304 + tl * 72 + dd];
        }
    } else {
#pragma unroll
        for (int i = 0; i < 2; ++i)
#pragma unroll
            for (int j = 0; j < 4; ++j)
#pragma unroll
                for (int g = 0; g < 4; ++g)
                    tw[(j * 16 + ln) * 40 + i * 16 + quad * 4 + g] = bf16_rne(acc[i][j][g]);
        __syncthreads();
        const size_t vbase = (size_t)(b * 8 + h) * 65536 + nnb;
#pragma unroll
        for (int p = 0; p < 2; ++p) {
            const int d = (p << 5) + (l >> 1);
            const int c = (l & 1) << 4;
            ushort_t* dst = &Vt[vbase + (size_t)d * 1024 + c];
            *(us8*)dst       = *(const us8*)&tw[d * 40 + c];
            *(us8*)(dst + 8) = *(const us8*)&tw[d * 40 + c + 8];
        }
    }
}

// out-proj: fp32 C + bias
__global__ __launch_bounds__(256) void gemm_out_mfma(
    const ushort_t* __restrict__ Ah, const ushort_t* __restrict__ Al,
    const ushort_t* __restrict__ Wh, const ushort_t* __restrict__ Wl,
    const float* __restrict__ bias, float* __restrict__ C) {
    GEMM_CORE(INNER_, Ah, Al, Wh, Wl)
#pragma unroll
    for (int i = 0; i < 2; ++i)
#pragma unroll
        for (int j = 0; j < 4; ++j) {
            const int col = n0 + j * 16 + ln;
            const float bb = bias[col];
#pragma unroll
            for (int g = 0; g < 4; ++g) {
                const int token = m0 + i * 16 + quad * 4 + g;
                C[(size_t)token * DIM_ + col] = acc[i][j][g] + bb;
            }
        }
}

// ---------------------------------------------------------------------------
// MFMA kNN attention. WG = 512 thr (8 waves) = (b,h, 16 q-rows).
// __launch_bounds__(512,4): LDS caps us at 2 WGs/CU = 4 waves/SIMD anyway,
// so allow 128 VGPRs/wave -- r6/r7's 60-64 VGPR allocation spilled the
// 16-entry key arrays to scratch (the hidden phase-2 wall).
// Phase 2: radix-4 select -- 16 iterations, 3 independent candidate
// thresholds per iteration (bits taken 2 at a time).
// ---------------------------------------------------------------------------
__global__ __launch_bounds__(512, 4) void attn_mfma(const ushort_t* __restrict__ Qh,
                                                    const ushort_t* __restrict__ Ql,
                                                    const ushort_t* __restrict__ Kh,
                                                    const ushort_t* __restrict__ Kl,
                                                    const ushort_t* __restrict__ Vt,
                                                    ushort_t* __restrict__ Oh,
                                                    ushort_t* __restrict__ Ol) {
    __shared__ float sdots[16 * 1024];        // 64 KB
    __shared__ float spartial[4][16][17];     // 4.25 KB j-split merge buffer

    const int t    = threadIdx.x;
    const int w    = t >> 6;        // wave 0..7
    const int l    = t & 63;
    const int ln   = l & 15;
    const int quad = l >> 4;
    const int wg   = blockIdx.x;
    const int bh   = wg & 31;       // XCD-local heads
    const int i0   = (wg >> 5) << 4;

    const size_t bhoff = (size_t)bh << 16;

    // ---- Q fragments (same for all waves)
    const ushort_t* qp  = Qh + bhoff + (size_t)(i0 + ln) * 64 + (quad << 3);
    const ushort_t* qlp = Ql + bhoff + (size_t)(i0 + ln) * 64 + (quad << 3);
    bf16x8 qh0 = *(const bf16x8*)qp;
    bf16x8 qh1 = *(const bf16x8*)(qp + 32);
    bf16x8 ql0 = *(const bf16x8*)qlp;
    bf16x8 ql1 = *(const bf16x8*)(qlp + 32);

    // ---- Phase 1: dots. wave w covers j in [w*128, w*128+128)
    for (int tt = 0; tt < 8; ++tt) {
        const int j0 = ((w << 3) + tt) << 4;
        const ushort_t* kp  = Kh + bhoff + (size_t)(j0 + ln) * 64 + (quad << 3);
        const ushort_t* klp = Kl + bhoff + (size_t)(j0 + ln) * 64 + (quad << 3);
        bf16x8 kh0 = *(const bf16x8*)kp;
        bf16x8 kh1 = *(const bf16x8*)(kp + 32);
        bf16x8 kl0 = *(const bf16x8*)klp;
        bf16x8 kl1 = *(const bf16x8*)(klp + 32);
        f32x4 acc = {0.f, 0.f, 0.f, 0.f};
        acc = __builtin_amdgcn_mfma_f32_16x16x32_bf16(qh0, kh0, acc, 0, 0, 0);
        acc = __builtin_amdgcn_mfma_f32_16x16x32_bf16(qh1, kh1, acc, 0, 0, 0);
        acc = __builtin_amdgcn_mfma_f32_16x16x32_bf16(qh0, kl0, acc, 0, 0, 0);
        acc = __builtin_amdgcn_mfma_f32_16x16x32_bf16(qh1, kl1, acc, 0, 0, 0);
        acc = __builtin_amdgcn_mfma_f32_16x16x32_bf16(ql0, kh0, acc, 0, 0, 0);
        acc = __builtin_amdgcn_mfma_f32_16x16x32_bf16(ql1, kh1, acc, 0, 0, 0);
#pragma unroll
        for (int g = 0; g < 4; ++g) {
            const int row = (quad << 2) + g;
            sdots[(row << 10) + ((j0 + ln) ^ ((row & 7) << 2))] = acc[g] * SCALE_;
        }
    }
    __syncthreads();

    // ---- Phase 2: per-row radix-4 top-k + softmax + in-place bf16 P
    ushort_t* sP = (ushort_t*)sdots;
    for (int rr = 0; rr < 2; ++rr) {
        const int r   = (w << 1) + rr;
        const int swz = (r & 7) << 2;
        const float* srow = &sdots[r << 10];
        // lane l holds keys for j = 4l + 256m + i  (m=0..3, i=0..3)
        unsigned key[16];
#pragma unroll
        for (int m = 0; m < 4; ++m) {
            f32x4 kv = *(const f32x4*)&srow[((l << 2) + (m << 8)) ^ swz];
#pragma unroll
            for (int i = 0; i < 4; ++i) key[(m << 2) + i] = f2key(kv[i]);
        }
        unsigned res = 0u;
        for (int sh = 30; sh >= 0; sh -= 2) {
            const unsigned t3 = res | (3u << sh);
            const unsigned t2 = res | (2u << sh);
            const unsigned t1 = res | (1u << sh);
            int l3 = 0, l2 = 0, l1 = 0;
#pragma unroll
            for (int m = 0; m < 16; ++m) {
                l3 += key[m] >= t3;
                l2 += key[m] >= t2;
                l1 += key[m] >= t1;
            }
            const int c3 = wave_count(l3);
            const int c2 = wave_count(l2);
            const int c1 = wave_count(l1);
            int hit = 0;
            if (c3 >= KK_)      { res = t3; hit = c3; }
            else if (c2 >= KK_) { res = t2; hit = c2; }
            else if (c1 >= KK_) { res = t1; hit = c1; }
            if (hit == KK_) break;   // wave-uniform: exact threshold found
        }
        const float thr = key2f(res);
        float lsum = 0.f;
#pragma unroll
        for (int m = 0; m < 16; ++m)
            lsum += (key[m] >= res) ? __expf(key2f(key[m]) - thr) : 0.f;
#pragma unroll
        for (int off = 32; off; off >>= 1) lsum += __shfl_xor(lsum, off, 64);
        const float inv = 1.f / lsum;
        // store P (bf16, phase-3 layout): j = 4l + 256m + i
#pragma unroll
        for (int m = 0; m < 4; ++m) {
            const int g = ((l >> 1) + (m << 5)) ^ (r & 7);
            ushort_t pk[4];
#pragma unroll
            for (int i = 0; i < 4; ++i) {
                const unsigned k = key[(m << 2) + i];
                const float p = (k >= res) ? __expf(key2f(k) - thr) * inv : 0.f;
                pk[i] = bf16_rne(p);
            }
            *(ushort4*)&sP[(r << 11) + (g << 3) + ((l & 1) << 2)] =
                make_ushort4(pk[0], pk[1], pk[2], pk[3]);
        }
    }
    __syncthreads();

    // ---- Phase 3: O = P @ V.  wave w: d-block (w&3), j-half (w&4 ? hi : lo)
    const int dblk  = w & 3;
    const int jbase = (w & 4) << 7;   // 0 or 512
    f32x4 oacc = {0.f, 0.f, 0.f, 0.f};
    const ushort_t* vp =
        Vt + bhoff + (size_t)((dblk << 4) + ln) * 1024 + (quad << 3) + jbase;
    const int prow = ln << 11;
    const int rsw  = ln & 7;
    for (int j0 = 0; j0 < 512; j0 += 32) {
        const int g = ((jbase + j0) >> 3) + quad;
        bf16x8 af = *(const bf16x8*)&sP[prow + ((g ^ rsw) << 3)];
        bf16x8 bv = *(const bf16x8*)(vp + j0);
        oacc = __builtin_amdgcn_mfma_f32_16x16x32_bf16(af, bv, oacc, 0, 0, 0);
    }
    if (w & 4) {
#pragma unroll
        for (int g = 0; g < 4; ++g)
            spartial[dblk][(quad << 2) + g][ln] = oacc[g];
    }
    __syncthreads();
    if (!(w & 4)) {
        const int b = bh >> 3, h = bh & 7;
        const size_t obase =
            ((size_t)(b << 10) + i0 + (quad << 2)) * 512 + (h << 6) + (dblk << 4) + ln;
#pragma unroll
        for (int g = 0; g < 4; ++g) {
            const float v = oacc[g] + spartial[dblk][(quad << 2) + g][ln];
            ushort_t hb = bf16_rne(v);
            Oh[obase + (size_t)g * 512] = hb;
            Ol[obase + (size_t)g * 512] = bf16_rne(v - bf16_f(hb));
        }
    }
}

extern "C" void kernel_launch(void* const* d_in, const int* in_sizes, int n_in,
                              void* d_out, int out_size, void* d_ws, size_t ws_size,
                              hipStream_t stream) {
    const float* x     = (const float*)d_in[0];
    const float* w_qkv = (const float*)d_in[1];
    const float* w_out = (const float*)d_in[2];
    const float* b_out = (const float*)d_in[3];
    float*       out   = (float*)d_out;

    const size_t ON  = (size_t)4096 * 512;
    const size_t WQT = (size_t)1536 * 512;
    const size_t WOT = (size_t)512 * 512;
    const size_t QK  = (size_t)32 * 1024 * 64;

    ushort_t* p    = (ushort_t*)d_ws;
    ushort_t* Oh   = p;            p += ON;
    ushort_t* Ol   = p;            p += ON;
    ushort_t* WqTh = p;            p += WQT;
    ushort_t* WqTl = p;            p += WQT;
    ushort_t* WoTh = p;            p += WOT;
    ushort_t* WoTl = p;            p += WOT;
    ushort_t* Qh   = p;            p += QK;
    ushort_t* Ql   = p;            p += QK;
    ushort_t* Kh   = p;            p += QK;
    ushort_t* Kl   = p;            p += QK;
    ushort_t* Vt   = p;            p += QK;   // total exactly 32 MiB

    conv_wT2<<<dim3(64, 16), 256, 0, stream>>>(w_qkv, w_out, WqTh, WqTl, WoTh, WoTl);

    // blockIdx.x = m-block so A tiles are XCD-local
    gemm_qkv_mfma<<<dim3(4096 / 128, TRIPLE_ / 64), 256, 0, stream>>>(
        x, WqTh, WqTl, Qh, Ql, Kh, Kl, Vt);

    attn_mfma<<<dim3(B_ * H_ * (N_ / 16)), 512, 0, stream>>>(Qh, Ql, Kh, Kl, Vt, Oh, Ol);

    gemm_out_mfma<<<dim3(4096 / 128, DIM_ / 64), 256, 0, stream>>>(
        Oh, Ol, WoTh, WoTl, b_out, out);
}

// Round 9
// 228.617 us; speedup vs baseline: 1.3066x; 1.3066x over previous
//
#include <hip/hip_runtime.h>
#include <cstddef>

#define B_      4
#define N_      1024
#define DIM_    512
#define H_      8
#define D_      64
#define INNER_  512
#define TRIPLE_ 1536
#define KK_     716        // int(1024 * 0.7)
#define SCALE_  0.125f     // 64^-0.5

typedef short bf16x8 __attribute__((ext_vector_type(8)));
typedef float f32x4  __attribute__((ext_vector_type(4)));
typedef unsigned short ushort_t;
typedef ushort_t us8 __attribute__((ext_vector_type(8)));

__device__ __forceinline__ unsigned short bf16_rne(float f) {
    unsigned u = __float_as_uint(f);
    return (unsigned short)((u + 0x7FFFu + ((u >> 16) & 1u)) >> 16);
}
__device__ __forceinline__ float bf16_f(unsigned short s) {
    return __uint_as_float((unsigned)s << 16);
}
// order-preserving float->uint key (descending float == descending uint)
__device__ __forceinline__ unsigned f2key(float f) {
    unsigned u = __float_as_uint(f);
    return u ^ ((u & 0x80000000u) ? 0xFFFFFFFFu : 0x80000000u);
}
__device__ __forceinline__ float key2f(unsigned k) {
    unsigned u = (k & 0x80000000u) ? (k ^ 0x80000000u) : ~k;
    return __uint_as_float(u);
}
// wave-wide count of per-lane tallies lc in [0,16] via 5 bit-plane ballots
__device__ __forceinline__ int wave_count(int lc) {
    int c = __popcll(__ballot(lc & 1));
    c += __popcll(__ballot(lc & 2)) << 1;
    c += __popcll(__ballot(lc & 4)) << 2;
    c += __popcll(__ballot(lc & 8)) << 3;
    c += __popcll(__ballot(lc & 16)) << 4;
    return c;
}
__device__ __forceinline__ int count_ge(const unsigned* key, unsigned kt) {
    int lc = 0;
#pragma unroll
    for (int m = 0; m < 16; ++m) lc += (key[m] >= kt) ? 1 : 0;
    return wave_count(lc);
}
// load 8 contiguous f32, emit hi/lo bf16 fragments
__device__ __forceinline__ void split8(const float* __restrict__ src,
                                       bf16x8& h8, bf16x8& l8) {
    float4 a = *(const float4*)src;
    float4 b = *(const float4*)(src + 4);
    float v[8] = {a.x, a.y, a.z, a.w, b.x, b.y, b.z, b.w};
#pragma unroll
    for (int i = 0; i < 8; ++i) {
        ushort_t hb = bf16_rne(v[i]);
        h8[i] = (short)hb;
        l8[i] = (short)bf16_rne(v[i] - bf16_f(hb));
    }
}

// ---------------------------------------------------------------------------
// Fused weight transpose+split: blocks [0,48) -> w_qkv, [48,64) -> w_out.
// ---------------------------------------------------------------------------
__global__ __launch_bounds__(256) void conv_wT2(const float* __restrict__ Wq,
                                                const float* __restrict__ Wo,
                                                ushort_t* __restrict__ WqTh,
                                                ushort_t* __restrict__ WqTl,
                                                ushort_t* __restrict__ WoTh,
                                                ushort_t* __restrict__ WoTl) {
    __shared__ float tile[32][33];
    const bool isQ = blockIdx.x < 48;
    const int  nb  = (isQ ? blockIdx.x : blockIdx.x - 48) * 32;
    const int  kb  = blockIdx.y * 32;
    const int  Nn  = isQ ? TRIPLE_ : DIM_;
    const float* W = isQ ? Wq : Wo;
    ushort_t* Th   = isQ ? WqTh : WoTh;
    ushort_t* Tl   = isQ ? WqTl : WoTl;
    const int tx = threadIdx.x & 31, ty = threadIdx.x >> 5;   // ty 0..7
    for (int yy = ty; yy < 32; yy += 8)
        tile[yy][tx] = W[(size_t)(kb + yy) * Nn + nb + tx];
    __syncthreads();
    for (int yy = ty; yy < 32; yy += 8) {
        float v = tile[tx][yy];
        ushort_t hb = bf16_rne(v);
        size_t idx = (size_t)(nb + yy) * DIM_ + kb + tx;
        Th[idx] = hb;
        Tl[idx] = bf16_rne(v - bf16_f(hb));
    }
}

// ---------------------------------------------------------------------------
// qkv GEMM: x fp32 A-side (in-register split), B tiles (hi+lo) staged in LDS
// once per block per k-step (4 waves share the same n0 tile).
// ---------------------------------------------------------------------------
__global__ __launch_bounds__(256) void gemm_qkv_mfma(
    const float* __restrict__ X,
    const ushort_t* __restrict__ Wh, const ushort_t* __restrict__ Wl,
    ushort_t* __restrict__ Qh, ushort_t* __restrict__ Ql,
    ushort_t* __restrict__ Kh, ushort_t* __restrict__ Kl,
    ushort_t* __restrict__ Vt) {
    __shared__ ushort_t stile[4][4608];   // 36 KB epilogue scratch
    __shared__ ushort_t BshH[2048];       // 4 KB: 64 rows x 4 quads x 8
    __shared__ ushort_t BshL[2048];
    const int t = threadIdx.x, w = t >> 6, l = t & 63;
    const int ln = l & 15, quad = l >> 4;
    const int n0 = blockIdx.y * 64;
    const int m0 = blockIdx.x * 128 + w * 32;
    f32x4 acc[2][4] = {};
    {
        const size_t xrow0 = (size_t)(m0 + ln) * DIM_;
        const size_t xrow1 = (size_t)(m0 + 16 + ln) * DIM_;
        const int srow = t >> 2;            // 0..63  (staging row)
        const int sk   = (t & 3) << 3;      // 0,8,16,24
        const size_t gb = (size_t)(n0 + srow) * DIM_ + sk;
        for (int k0 = 0; k0 < DIM_; k0 += 32) {
            us8 sh = *(const us8*)&Wh[gb + k0];
            us8 sl = *(const us8*)&Wl[gb + k0];
            *(us8*)&BshH[t << 3] = sh;
            *(us8*)&BshL[t << 3] = sl;
            __syncthreads();
            const int ko = k0 + quad * 8;
            bf16x8 ah0, al0, ah1, al1;
            split8(&X[xrow0 + ko], ah0, al0);
            split8(&X[xrow1 + ko], ah1, al1);
#pragma unroll
            for (int j = 0; j < 4; ++j) {
                const int slot = (((j << 4) + ln) << 5) + (quad << 3);
                bf16x8 bh = *(const bf16x8*)&BshH[slot];
                bf16x8 bl = *(const bf16x8*)&BshL[slot];
                acc[0][j] = __builtin_amdgcn_mfma_f32_16x16x32_bf16(ah0, bh, acc[0][j], 0, 0, 0);
                acc[0][j] = __builtin_amdgcn_mfma_f32_16x16x32_bf16(al0, bh, acc[0][j], 0, 0, 0);
                acc[0][j] = __builtin_amdgcn_mfma_f32_16x16x32_bf16(ah0, bl, acc[0][j], 0, 0, 0);
                acc[1][j] = __builtin_amdgcn_mfma_f32_16x16x32_bf16(ah1, bh, acc[1][j], 0, 0, 0);
                acc[1][j] = __builtin_amdgcn_mfma_f32_16x16x32_bf16(al1, bh, acc[1][j], 0, 0, 0);
                acc[1][j] = __builtin_amdgcn_mfma_f32_16x16x32_bf16(ah1, bl, acc[1][j], 0, 0, 0);
            }
            __syncthreads();
        }
    }
    const int sec = n0 >> 9;           // block-uniform
    const int h   = (n0 >> 6) & 7;
    ushort_t* tw  = stile[w];
    const int b = m0 >> 10, nnb = m0 & 1023;
    if (sec < 2) {
        ushort_t* Hp = sec ? Kh : Qh;
        ushort_t* Lp = sec ? Kl : Ql;
#pragma unroll
        for (int i = 0; i < 2; ++i)
#pragma unroll
            for (int j = 0; j < 4; ++j)
#pragma unroll
                for (int g = 0; g < 4; ++g) {
                    const float v = acc[i][j][g];
                    const ushort_t hb = bf16_rne(v);
                    const ushort_t lb = bf16_rne(v - bf16_f(hb));
                    const int tok = i * 16 + quad * 4 + g;
                    const int d   = j * 16 + ln;
                    tw[tok * 72 + d]        = hb;
                    tw[2304 + tok * 72 + d] = lb;
                }
        __syncthreads();
        const size_t rowbase = ((size_t)(b * 8 + h) * 1024 + nnb) * 64;
        const int dd = (l & 7) * 8;
#pragma unroll
        for (int s = 0; s < 4; ++s) {
            const int tl = s * 8 + (l >> 3);
            const size_t off = rowbase + (size_t)tl * 64 + dd;
            *(us8*)&Hp[off] = *(const us8*)&tw[tl * 72 + dd];
            *(us8*)&Lp[off] = *(const us8*)&tw[2304 + tl * 72 + dd];
        }
    } else {
#pragma unroll
        for (int i = 0; i < 2; ++i)
#pragma unroll
            for (int j = 0; j < 4; ++j)
#pragma unroll
                for (int g = 0; g < 4; ++g)
                    tw[(j * 16 + ln) * 40 + i * 16 + quad * 4 + g] = bf16_rne(acc[i][j][g]);
        __syncthreads();
        const size_t vbase = (size_t)(b * 8 + h) * 65536 + nnb;
#pragma unroll
        for (int p = 0; p < 2; ++p) {
            const int d = (p << 5) + (l >> 1);
            const int c = (l & 1) << 4;
            ushort_t* dst = &Vt[vbase + (size_t)d * 1024 + c];
            *(us8*)dst       = *(const us8*)&tw[d * 40 + c];
            *(us8*)(dst + 8) = *(const us8*)&tw[d * 40 + c + 8];
        }
    }
}

// ---------------------------------------------------------------------------
// out-proj: bf16 hi/lo A, B staged in LDS, fp32 C + bias
// ---------------------------------------------------------------------------
__global__ __launch_bounds__(256) void gemm_out_mfma(
    const ushort_t* __restrict__ Ah, const ushort_t* __restrict__ Al,
    const ushort_t* __restrict__ Wh, const ushort_t* __restrict__ Wl,
    const float* __restrict__ bias, float* __restrict__ C) {
    __shared__ ushort_t BshH[2048];
    __shared__ ushort_t BshL[2048];
    const int t = threadIdx.x, w = t >> 6, l = t & 63;
    const int ln = l & 15, quad = l >> 4;
    const int n0 = blockIdx.y * 64;
    const int m0 = blockIdx.x * 128 + w * 32;
    f32x4 acc[2][4] = {};
    {
        const size_t arow0 = (size_t)(m0 + ln) * INNER_;
        const size_t arow1 = (size_t)(m0 + 16 + ln) * INNER_;
        const int srow = t >> 2;
        const int sk   = (t & 3) << 3;
        const size_t gb = (size_t)(n0 + srow) * INNER_ + sk;
        for (int k0 = 0; k0 < INNER_; k0 += 32) {
            us8 sh = *(const us8*)&Wh[gb + k0];
            us8 sl = *(const us8*)&Wl[gb + k0];
            *(us8*)&BshH[t << 3] = sh;
            *(us8*)&BshL[t << 3] = sl;
            __syncthreads();
            const int ko = k0 + quad * 8;
            bf16x8 ah0 = *(const bf16x8*)&Ah[arow0 + ko];
            bf16x8 al0 = *(const bf16x8*)&Al[arow0 + ko];
            bf16x8 ah1 = *(const bf16x8*)&Ah[arow1 + ko];
            bf16x8 al1 = *(const bf16x8*)&Al[arow1 + ko];
#pragma unroll
            for (int j = 0; j < 4; ++j) {
                const int slot = (((j << 4) + ln) << 5) + (quad << 3);
                bf16x8 bh = *(const bf16x8*)&BshH[slot];
                bf16x8 bl = *(const bf16x8*)&BshL[slot];
                acc[0][j] = __builtin_amdgcn_mfma_f32_16x16x32_bf16(ah0, bh, acc[0][j], 0, 0, 0);
                acc[0][j] = __builtin_amdgcn_mfma_f32_16x16x32_bf16(al0, bh, acc[0][j], 0, 0, 0);
                acc[0][j] = __builtin_amdgcn_mfma_f32_16x16x32_bf16(ah0, bl, acc[0][j], 0, 0, 0);
                acc[1][j] = __builtin_amdgcn_mfma_f32_16x16x32_bf16(ah1, bh, acc[1][j], 0, 0, 0);
                acc[1][j] = __builtin_amdgcn_mfma_f32_16x16x32_bf16(al1, bh, acc[1][j], 0, 0, 0);
                acc[1][j] = __builtin_amdgcn_mfma_f32_16x16x32_bf16(ah1, bl, acc[1][j], 0, 0, 0);
            }
            __syncthreads();
        }
    }
#pragma unroll
    for (int i = 0; i < 2; ++i)
#pragma unroll
        for (int j = 0; j < 4; ++j) {
            const int col = n0 + j * 16 + ln;
            const float bb = bias[col];
#pragma unroll
            for (int g = 0; g < 4; ++g) {
                const int token = m0 + i * 16 + quad * 4 + g;
                C[(size_t)token * DIM_ + col] = acc[i][j][g] + bb;
            }
        }
}

// ---------------------------------------------------------------------------
// MFMA kNN attention. WG = 512 thr (8 waves) = (b,h, 16 q-rows).
// Phase 2: interpolation-seeded exact threshold search. Dots per row are
// ~Gaussian: seed t = mu - 0.522*sigma (the 716/1024 quantile), then secant
// on the empirical count with a bracket. Exact exit at count==KK_ (any t in
// the order-statistic gap keeps exactly the top-KK_ set). Guaranteed-exact
// uint-bisection fallback. ~5 count-trials/row vs 19 for bit-binary search
// (phase 2 is VALU-throughput bound -- r8 showed work ~ time).
// ---------------------------------------------------------------------------
__global__ __launch_bounds__(512, 4) void attn_mfma(const ushort_t* __restrict__ Qh,
                                                    const ushort_t* __restrict__ Ql,
                                                    const ushort_t* __restrict__ Kh,
                                                    const ushort_t* __restrict__ Kl,
                                                    const ushort_t* __restrict__ Vt,
                                                    ushort_t* __restrict__ Oh,
                                                    ushort_t* __restrict__ Ol) {
    __shared__ float sdots[16 * 1024];        // 64 KB
    __shared__ float spartial[4][16][17];     // 4.25 KB j-split merge buffer

    const int t    = threadIdx.x;
    const int w    = t >> 6;        // wave 0..7
    const int l    = t & 63;
    const int ln   = l & 15;
    const int quad = l >> 4;
    const int wg   = blockIdx.x;
    const int bh   = wg & 31;       // XCD-local heads
    const int i0   = (wg >> 5) << 4;

    const size_t bhoff = (size_t)bh << 16;

    // ---- Q fragments (same for all waves)
    const ushort_t* qp  = Qh + bhoff + (size_t)(i0 + ln) * 64 + (quad << 3);
    const ushort_t* qlp = Ql + bhoff + (size_t)(i0 + ln) * 64 + (quad << 3);
    bf16x8 qh0 = *(const bf16x8*)qp;
    bf16x8 qh1 = *(const bf16x8*)(qp + 32);
    bf16x8 ql0 = *(const bf16x8*)qlp;
    bf16x8 ql1 = *(const bf16x8*)(qlp + 32);

    // ---- Phase 1: dots. wave w covers j in [w*128, w*128+128)
    for (int tt = 0; tt < 8; ++tt) {
        const int j0 = ((w << 3) + tt) << 4;
        const ushort_t* kp  = Kh + bhoff + (size_t)(j0 + ln) * 64 + (quad << 3);
        const ushort_t* klp = Kl + bhoff + (size_t)(j0 + ln) * 64 + (quad << 3);
        bf16x8 kh0 = *(const bf16x8*)kp;
        bf16x8 kh1 = *(const bf16x8*)(kp + 32);
        bf16x8 kl0 = *(const bf16x8*)klp;
        bf16x8 kl1 = *(const bf16x8*)(klp + 32);
        f32x4 acc = {0.f, 0.f, 0.f, 0.f};
        acc = __builtin_amdgcn_mfma_f32_16x16x32_bf16(qh0, kh0, acc, 0, 0, 0);
        acc = __builtin_amdgcn_mfma_f32_16x16x32_bf16(qh1, kh1, acc, 0, 0, 0);
        acc = __builtin_amdgcn_mfma_f32_16x16x32_bf16(qh0, kl0, acc, 0, 0, 0);
        acc = __builtin_amdgcn_mfma_f32_16x16x32_bf16(qh1, kl1, acc, 0, 0, 0);
        acc = __builtin_amdgcn_mfma_f32_16x16x32_bf16(ql0, kh0, acc, 0, 0, 0);
        acc = __builtin_amdgcn_mfma_f32_16x16x32_bf16(ql1, kh1, acc, 0, 0, 0);
#pragma unroll
        for (int g = 0; g < 4; ++g) {
            const int row = (quad << 2) + g;
            sdots[(row << 10) + ((j0 + ln) ^ ((row & 7) << 2))] = acc[g] * SCALE_;
        }
    }
    __syncthreads();

    // ---- Phase 2: per-row interpolated top-k + softmax + in-place bf16 P
    ushort_t* sP = (ushort_t*)sdots;
    for (int rr = 0; rr < 2; ++rr) {
        const int r   = (w << 1) + rr;
        const int swz = (r & 7) << 2;
        const float* srow = &sdots[r << 10];
        // lane l holds keys for j = 4l + 256m + i  (m=0..3, i=0..3)
        unsigned key[16];
        float s = 0.f, s2 = 0.f;
#pragma unroll
        for (int m = 0; m < 4; ++m) {
            f32x4 kv = *(const f32x4*)&srow[((l << 2) + (m << 8)) ^ swz];
#pragma unroll
            for (int i = 0; i < 4; ++i) {
                key[(m << 2) + i] = f2key(kv[i]);
                s  += kv[i];
                s2 += kv[i] * kv[i];
            }
        }
#pragma unroll
        for (int off = 32; off; off >>= 1) {
            s  += __shfl_xor(s, off, 64);
            s2 += __shfl_xor(s2, off, 64);
        }
        const float mu = s * (1.0f / 1024.f);
        const float sg = sqrtf(fmaxf(s2 * (1.0f / 1024.f) - mu * mu, 1e-20f));

        unsigned res = 0u;
        bool found = false;
        float tlo = 0.f, thi = 0.f;
        int   clo = 0,   chi = 0;
        bool  hlo = false, hhi = false;
        float tcur = mu - 0.52189f * sg;      // seed at the 716/1024 quantile
        for (int it = 0; it < 10; ++it) {
            const unsigned kt = f2key(tcur);
            const int c = count_ge(key, kt);
            if (c == KK_) { res = kt; found = true; break; }
            if (c > KK_) { tlo = tcur; clo = c; hlo = true; }
            else         { thi = tcur; chi = c; hhi = true; }
            float tn;
            if (hlo && hhi) {
                tn = tlo + (thi - tlo) * ((float)(clo - KK_) / (float)(clo - chi));
            } else {
                const float z    = (tcur - mu) / sg;
                const float dens = fmaxf(408.5f * __expf(-0.5f * z * z) / sg, 1.f);
                tn = tcur + (float)(c - KK_) / dens;
            }
            if (hlo && !(tn > tlo)) tn = hhi ? 0.5f * (tlo + thi) : tlo + 0.25f * sg;
            if (hhi && !(tn < thi)) tn = hlo ? 0.5f * (tlo + thi) : thi - 0.25f * sg;
            tcur = tn;
        }
        if (!found) {
            // exact fallback: uint bisection on the remaining bracket
            unsigned klo = hlo ? f2key(tlo) : 0u;
            unsigned khi = hhi ? f2key(thi) : 0xFFFFFFFFu;
            while (khi - klo > 1u) {
                const unsigned km = klo + ((khi - klo) >> 1);
                const int c = count_ge(key, km);
                if (c >= KK_) { klo = km; if (c == KK_) break; }
                else khi = km;
            }
            res = klo;
        }

        const float thr = key2f(res);
        float pv[16];
        float lsum = 0.f;
#pragma unroll
        for (int m = 0; m < 16; ++m) {
            const unsigned k = key[m];
            float p = (k >= res) ? __expf(key2f(k) - thr) : 0.f;
            pv[m] = p;
            lsum += p;
        }
#pragma unroll
        for (int off = 32; off; off >>= 1) lsum += __shfl_xor(lsum, off, 64);
        const float inv = 1.f / lsum;
        // store P (bf16, phase-3 layout): j = 4l + 256m + i
#pragma unroll
        for (int m = 0; m < 4; ++m) {
            const int g = ((l >> 1) + (m << 5)) ^ (r & 7);
            ushort4 pk = make_ushort4(bf16_rne(pv[(m << 2) + 0] * inv),
                                      bf16_rne(pv[(m << 2) + 1] * inv),
                                      bf16_rne(pv[(m << 2) + 2] * inv),
                                      bf16_rne(pv[(m << 2) + 3] * inv));
            *(ushort4*)&sP[(r << 11) + (g << 3) + ((l & 1) << 2)] = pk;
        }
    }
    __syncthreads();

    // ---- Phase 3: O = P @ V.  wave w: d-block (w&3), j-half (w&4 ? hi : lo)
    const int dblk  = w & 3;
    const int jbase = (w & 4) << 7;   // 0 or 512
    f32x4 oacc = {0.f, 0.f, 0.f, 0.f};
    const ushort_t* vp =
        Vt + bhoff + (size_t)((dblk << 4) + ln) * 1024 + (quad << 3) + jbase;
    const int prow = ln << 11;
    const int rsw  = ln & 7;
    for (int j0 = 0; j0 < 512; j0 += 32) {
        const int g = ((jbase + j0) >> 3) + quad;
        bf16x8 af = *(const bf16x8*)&sP[prow + ((g ^ rsw) << 3)];
        bf16x8 bv = *(const bf16x8*)(vp + j0);
        oacc = __builtin_amdgcn_mfma_f32_16x16x32_bf16(af, bv, oacc, 0, 0, 0);
    }
    if (w & 4) {
#pragma unroll
        for (int g = 0; g < 4; ++g)
            spartial[dblk][(quad << 2) + g][ln] = oacc[g];
    }
    __syncthreads();
    if (!(w & 4)) {
        const int b = bh >> 3, h = bh & 7;
        const size_t obase =
            ((size_t)(b << 10) + i0 + (quad << 2)) * 512 + (h << 6) + (dblk << 4) + ln;
#pragma unroll
        for (int g = 0; g < 4; ++g) {
            const float v = oacc[g] + spartial[dblk][(quad << 2) + g][ln];
            ushort_t hb = bf16_rne(v);
            Oh[obase + (size_t)g * 512] = hb;
            Ol[obase + (size_t)g * 512] = bf16_rne(v - bf16_f(hb));
        }
    }
}

extern "C" void kernel_launch(void* const* d_in, const int* in_sizes, int n_in,
                              void* d_out, int out_size, void* d_ws, size_t ws_size,
                              hipStream_t stream) {
    const float* x     = (const float*)d_in[0];
    const float* w_qkv = (const float*)d_in[1];
    const float* w_out = (const float*)d_in[2];
    const float* b_out = (const float*)d_in[3];
    float*       out   = (float*)d_out;

    const size_t ON  = (size_t)4096 * 512;
    const size_t WQT = (size_t)1536 * 512;
    const size_t WOT = (size_t)512 * 512;
    const size_t QK  = (size_t)32 * 1024 * 64;

    ushort_t* p    = (ushort_t*)d_ws;
    ushort_t* Oh   = p;            p += ON;
    ushort_t* Ol   = p;            p += ON;
    ushort_t* WqTh = p;            p += WQT;
    ushort_t* WqTl = p;            p += WQT;
    ushort_t* WoTh = p;            p += WOT;
    ushort_t* WoTl = p;            p += WOT;
    ushort_t* Qh   = p;            p += QK;
    ushort_t* Ql   = p;            p += QK;
    ushort_t* Kh   = p;            p += QK;
    ushort_t* Kl   = p;            p += QK;
    ushort_t* Vt   = p;            p += QK;   // total exactly 32 MiB

    conv_wT2<<<dim3(64, 16), 256, 0, stream>>>(w_qkv, w_out, WqTh, WqTl, WoTh, WoTl);

    // blockIdx.x = m-block so A tiles are XCD-local
    gemm_qkv_mfma<<<dim3(4096 / 128, TRIPLE_ / 64), 256, 0, stream>>>(
        x, WqTh, WqTl, Qh, Ql, Kh, Kl, Vt);

    attn_mfma<<<dim3(B_ * H_ * (N_ / 16)), 512, 0, stream>>>(Qh, Ql, Kh, Kl, Vt, Oh, Ol);

    gemm_out_mfma<<<dim3(4096 / 128, DIM_ / 64), 256, 0, stream>>>(
        Oh, Ol, WoTh, WoTl, b_out, out);
}

// Round 10
// 225.397 us; speedup vs baseline: 1.3252x; 1.0143x over previous
//
#include <hip/hip_runtime.h>
#include <cstddef>

#define B_      4
#define N_      1024
#define DIM_    512
#define H_      8
#define D_      64
#define INNER_  512
#define TRIPLE_ 1536
#define KK_     716        // int(1024 * 0.7)
#define SCALE_  0.125f     // 64^-0.5

typedef short bf16x8 __attribute__((ext_vector_type(8)));
typedef float f32x4  __attribute__((ext_vector_type(4)));
typedef unsigned short ushort_t;
typedef ushort_t us8 __attribute__((ext_vector_type(8)));

__device__ __forceinline__ unsigned short bf16_rne(float f) {
    unsigned u = __float_as_uint(f);
    return (unsigned short)((u + 0x7FFFu + ((u >> 16) & 1u)) >> 16);
}
__device__ __forceinline__ float bf16_f(unsigned short s) {
    return __uint_as_float((unsigned)s << 16);
}
// order-preserving float->uint key (descending float == descending uint)
__device__ __forceinline__ unsigned f2key(float f) {
    unsigned u = __float_as_uint(f);
    return u ^ ((u & 0x80000000u) ? 0xFFFFFFFFu : 0x80000000u);
}
__device__ __forceinline__ float key2f(unsigned k) {
    unsigned u = (k & 0x80000000u) ? (k ^ 0x80000000u) : ~k;
    return __uint_as_float(u);
}
// wave-wide count of per-lane tallies lc in [0,16] via 5 bit-plane ballots
__device__ __forceinline__ int wave_count(int lc) {
    int c = __popcll(__ballot(lc & 1));
    c += __popcll(__ballot(lc & 2)) << 1;
    c += __popcll(__ballot(lc & 4)) << 2;
    c += __popcll(__ballot(lc & 8)) << 3;
    c += __popcll(__ballot(lc & 16)) << 4;
    return c;
}
__device__ __forceinline__ int count_ge(const unsigned* key, unsigned kt) {
    int lc = 0;
#pragma unroll
    for (int m = 0; m < 16; ++m) lc += (key[m] >= kt) ? 1 : 0;
    return wave_count(lc);
}
// exact top-KK_ threshold: interpolation-seeded secant with exact-gap exit,
// guaranteed-exact uint bisection fallback
__device__ __forceinline__ unsigned topk_thresh(const unsigned* key, float mu, float sg) {
    unsigned res = 0u;
    bool found = false;
    float tlo = 0.f, thi = 0.f;
    int   clo = 0,   chi = 0;
    bool  hlo = false, hhi = false;
    float tcur = mu - 0.52189f * sg;      // seed at the 716/1024 quantile
    for (int it = 0; it < 10; ++it) {
        const unsigned kt = f2key(tcur);
        const int c = count_ge(key, kt);
        if (c == KK_) { res = kt; found = true; break; }
        if (c > KK_) { tlo = tcur; clo = c; hlo = true; }
        else         { thi = tcur; chi = c; hhi = true; }
        float tn;
        if (hlo && hhi) {
            tn = tlo + (thi - tlo) * ((float)(clo - KK_) / (float)(clo - chi));
        } else {
            const float z    = (tcur - mu) / sg;
            const float dens = fmaxf(408.5f * __expf(-0.5f * z * z) / sg, 1.f);
            tn = tcur + (float)(c - KK_) / dens;
        }
        if (hlo && !(tn > tlo)) tn = hhi ? 0.5f * (tlo + thi) : tlo + 0.25f * sg;
        if (hhi && !(tn < thi)) tn = hlo ? 0.5f * (tlo + thi) : thi - 0.25f * sg;
        tcur = tn;
    }
    if (!found) {
        unsigned klo = hlo ? f2key(tlo) : 0u;
        unsigned khi = hhi ? f2key(thi) : 0xFFFFFFFFu;
        while (khi - klo > 1u) {
            const unsigned km = klo + ((khi - klo) >> 1);
            const int c = count_ge(key, km);
            if (c >= KK_) { klo = km; if (c == KK_) break; }
            else khi = km;
        }
        res = klo;
    }
    return res;
}
// load 8 contiguous f32, emit hi/lo bf16 fragments
__device__ __forceinline__ void split8(const float* __restrict__ src,
                                       bf16x8& h8, bf16x8& l8) {
    float4 a = *(const float4*)src;
    float4 b = *(const float4*)(src + 4);
    float v[8] = {a.x, a.y, a.z, a.w, b.x, b.y, b.z, b.w};
#pragma unroll
    for (int i = 0; i < 8; ++i) {
        ushort_t hb = bf16_rne(v[i]);
        h8[i] = (short)hb;
        l8[i] = (short)bf16_rne(v[i] - bf16_f(hb));
    }
}

// ---------------------------------------------------------------------------
// Fused weight transpose+split: blocks [0,48) -> w_qkv, [48,64) -> w_out.
// ---------------------------------------------------------------------------
__global__ __launch_bounds__(256) void conv_wT2(const float* __restrict__ Wq,
                                                const float* __restrict__ Wo,
                                                ushort_t* __restrict__ WqTh,
                                                ushort_t* __restrict__ WqTl,
                                                ushort_t* __restrict__ WoTh,
                                                ushort_t* __restrict__ WoTl) {
    __shared__ float tile[32][33];
    const bool isQ = blockIdx.x < 48;
    const int  nb  = (isQ ? blockIdx.x : blockIdx.x - 48) * 32;
    const int  kb  = blockIdx.y * 32;
    const int  Nn  = isQ ? TRIPLE_ : DIM_;
    const float* W = isQ ? Wq : Wo;
    ushort_t* Th   = isQ ? WqTh : WoTh;
    ushort_t* Tl   = isQ ? WqTl : WoTl;
    const int tx = threadIdx.x & 31, ty = threadIdx.x >> 5;   // ty 0..7
    for (int yy = ty; yy < 32; yy += 8)
        tile[yy][tx] = W[(size_t)(kb + yy) * Nn + nb + tx];
    __syncthreads();
    for (int yy = ty; yy < 32; yy += 8) {
        float v = tile[tx][yy];
        ushort_t hb = bf16_rne(v);
        size_t idx = (size_t)(nb + yy) * DIM_ + kb + tx;
        Th[idx] = hb;
        Tl[idx] = bf16_rne(v - bf16_f(hb));
    }
}

// ---------------------------------------------------------------------------
// qkv GEMM: x fp32 A-side (in-register split), B tiles double-buffered in
// LDS -- next k-step's global loads issue BEFORE the barrier, ONE barrier
// per k-step (16 vs 32), loads stay in flight across barrier+compute.
// ---------------------------------------------------------------------------
__global__ __launch_bounds__(256) void gemm_qkv_mfma(
    const float* __restrict__ X,
    const ushort_t* __restrict__ Wh, const ushort_t* __restrict__ Wl,
    ushort_t* __restrict__ Qh, ushort_t* __restrict__ Ql,
    ushort_t* __restrict__ Kh, ushort_t* __restrict__ Kl,
    ushort_t* __restrict__ Vt) {
    __shared__ ushort_t stile[4][4608];   // 36 KB epilogue scratch
    __shared__ ushort_t BshH[2][2048];    // 8 KB x2 double buffer
    __shared__ ushort_t BshL[2][2048];
    const int t = threadIdx.x, w = t >> 6, l = t & 63;
    const int ln = l & 15, quad = l >> 4;
    const int n0 = blockIdx.y * 64;
    const int m0 = blockIdx.x * 128 + w * 32;
    f32x4 acc[2][4] = {};
    {
        const size_t xrow0 = (size_t)(m0 + ln) * DIM_;
        const size_t xrow1 = (size_t)(m0 + 16 + ln) * DIM_;
        const int srow = t >> 2;            // 0..63  (staging row)
        const int sk   = (t & 3) << 3;      // 0,8,16,24
        const size_t gb = (size_t)(n0 + srow) * DIM_ + sk;
        us8 nh = *(const us8*)&Wh[gb];
        us8 nl = *(const us8*)&Wl[gb];
        *(us8*)&BshH[0][t * 8] = nh;
        *(us8*)&BshL[0][t * 8] = nl;
        int cur = 0;
        for (int k0 = 0; k0 < DIM_; k0 += 32) {
            const bool more = (k0 + 32) < DIM_;
            const size_t gnext = gb + (size_t)(more ? k0 + 32 : 0);
            nh = *(const us8*)&Wh[gnext];           // issue BEFORE barrier
            nl = *(const us8*)&Wl[gnext];
            __syncthreads();                        // buf[cur] ready
            const int ko = k0 + quad * 8;
            bf16x8 ah0, al0, ah1, al1;
            split8(&X[xrow0 + ko], ah0, al0);
            split8(&X[xrow1 + ko], ah1, al1);
#pragma unroll
            for (int j = 0; j < 4; ++j) {
                const int slot = (((j << 4) + ln) << 5) + (quad << 3);
                bf16x8 bh = *(const bf16x8*)&BshH[cur][slot];
                bf16x8 bl = *(const bf16x8*)&BshL[cur][slot];
                acc[0][j] = __builtin_amdgcn_mfma_f32_16x16x32_bf16(ah0, bh, acc[0][j], 0, 0, 0);
                acc[0][j] = __builtin_amdgcn_mfma_f32_16x16x32_bf16(al0, bh, acc[0][j], 0, 0, 0);
                acc[0][j] = __builtin_amdgcn_mfma_f32_16x16x32_bf16(ah0, bl, acc[0][j], 0, 0, 0);
                acc[1][j] = __builtin_amdgcn_mfma_f32_16x16x32_bf16(ah1, bh, acc[1][j], 0, 0, 0);
                acc[1][j] = __builtin_amdgcn_mfma_f32_16x16x32_bf16(al1, bh, acc[1][j], 0, 0, 0);
                acc[1][j] = __builtin_amdgcn_mfma_f32_16x16x32_bf16(ah1, bl, acc[1][j], 0, 0, 0);
            }
            if (more) {
                *(us8*)&BshH[cur ^ 1][t * 8] = nh;
                *(us8*)&BshL[cur ^ 1][t * 8] = nl;
            }
            cur ^= 1;
        }
    }
    const int sec = n0 >> 9;           // block-uniform
    const int h   = (n0 >> 6) & 7;
    ushort_t* tw  = stile[w];
    const int b = m0 >> 10, nnb = m0 & 1023;
    if (sec < 2) {
        ushort_t* Hp = sec ? Kh : Qh;
        ushort_t* Lp = sec ? Kl : Ql;
#pragma unroll
        for (int i = 0; i < 2; ++i)
#pragma unroll
            for (int j = 0; j < 4; ++j)
#pragma unroll
                for (int g = 0; g < 4; ++g) {
                    const float v = acc[i][j][g];
                    const ushort_t hb = bf16_rne(v);
                    const ushort_t lb = bf16_rne(v - bf16_f(hb));
                    const int tok = i * 16 + quad * 4 + g;
                    const int d   = j * 16 + ln;
                    tw[tok * 72 + d]        = hb;
                    tw[2304 + tok * 72 + d] = lb;
                }
        __syncthreads();
        const size_t rowbase = ((size_t)(b * 8 + h) * 1024 + nnb) * 64;
        const int dd = (l & 7) * 8;
#pragma unroll
        for (int s = 0; s < 4; ++s) {
            const int tl = s * 8 + (l >> 3);
            const size_t off = rowbase + (size_t)tl * 64 + dd;
            *(us8*)&Hp[off] = *(const us8*)&tw[tl * 72 + dd];
            *(us8*)&Lp[off] = *(const us8*)&tw[2304 + tl * 72 + dd];
        }
    } else {
#pragma unroll
        for (int i = 0; i < 2; ++i)
#pragma unroll
            for (int j = 0; j < 4; ++j)
#pragma unroll
                for (int g = 0; g < 4; ++g)
                    tw[(j * 16 + ln) * 40 + i * 16 + quad * 4 + g] = bf16_rne(acc[i][j][g]);
        __syncthreads();
        const size_t vbase = (size_t)(b * 8 + h) * 65536 + nnb;
#pragma unroll
        for (int p = 0; p < 2; ++p) {
            const int d = (p << 5) + (l >> 1);
            const int c = (l & 1) << 4;
            ushort_t* dst = &Vt[vbase + (size_t)d * 1024 + c];
            *(us8*)dst       = *(const us8*)&tw[d * 40 + c];
            *(us8*)(dst + 8) = *(const us8*)&tw[d * 40 + c + 8];
        }
    }
}

// ---------------------------------------------------------------------------
// out-proj: bf16 hi/lo A, B double-buffered in LDS, fp32 C + bias
// ---------------------------------------------------------------------------
__global__ __launch_bounds__(256) void gemm_out_mfma(
    const ushort_t* __restrict__ Ah, const ushort_t* __restrict__ Al,
    const ushort_t* __restrict__ Wh, const ushort_t* __restrict__ Wl,
    const float* __restrict__ bias, float* __restrict__ C) {
    __shared__ ushort_t BshH[2][2048];
    __shared__ ushort_t BshL[2][2048];
    const int t = threadIdx.x, w = t >> 6, l = t & 63;
    const int ln = l & 15, quad = l >> 4;
    const int n0 = blockIdx.y * 64;
    const int m0 = blockIdx.x * 128 + w * 32;
    f32x4 acc[2][4] = {};
    {
        const size_t arow0 = (size_t)(m0 + ln) * INNER_;
        const size_t arow1 = (size_t)(m0 + 16 + ln) * INNER_;
        const int srow = t >> 2;
        const int sk   = (t & 3) << 3;
        const size_t gb = (size_t)(n0 + srow) * INNER_ + sk;
        us8 nh = *(const us8*)&Wh[gb];
        us8 nl = *(const us8*)&Wl[gb];
        *(us8*)&BshH[0][t * 8] = nh;
        *(us8*)&BshL[0][t * 8] = nl;
        int cur = 0;
        for (int k0 = 0; k0 < INNER_; k0 += 32) {
            const bool more = (k0 + 32) < INNER_;
            const size_t gnext = gb + (size_t)(more ? k0 + 32 : 0);
            nh = *(const us8*)&Wh[gnext];
            nl = *(const us8*)&Wl[gnext];
            __syncthreads();
            const int ko = k0 + quad * 8;
            bf16x8 ah0 = *(const bf16x8*)&Ah[arow0 + ko];
            bf16x8 al0 = *(const bf16x8*)&Al[arow0 + ko];
            bf16x8 ah1 = *(const bf16x8*)&Ah[arow1 + ko];
            bf16x8 al1 = *(const bf16x8*)&Al[arow1 + ko];
#pragma unroll
            for (int j = 0; j < 4; ++j) {
                const int slot = (((j << 4) + ln) << 5) + (quad << 3);
                bf16x8 bh = *(const bf16x8*)&BshH[cur][slot];
                bf16x8 bl = *(const bf16x8*)&BshL[cur][slot];
                acc[0][j] = __builtin_amdgcn_mfma_f32_16x16x32_bf16(ah0, bh, acc[0][j], 0, 0, 0);
                acc[0][j] = __builtin_amdgcn_mfma_f32_16x16x32_bf16(al0, bh, acc[0][j], 0, 0, 0);
                acc[0][j] = __builtin_amdgcn_mfma_f32_16x16x32_bf16(ah0, bl, acc[0][j], 0, 0, 0);
                acc[1][j] = __builtin_amdgcn_mfma_f32_16x16x32_bf16(ah1, bh, acc[1][j], 0, 0, 0);
                acc[1][j] = __builtin_amdgcn_mfma_f32_16x16x32_bf16(al1, bh, acc[1][j], 0, 0, 0);
                acc[1][j] = __builtin_amdgcn_mfma_f32_16x16x32_bf16(ah1, bl, acc[1][j], 0, 0, 0);
            }
            if (more) {
                *(us8*)&BshH[cur ^ 1][t * 8] = nh;
                *(us8*)&BshL[cur ^ 1][t * 8] = nl;
            }
            cur ^= 1;
        }
    }
#pragma unroll
    for (int i = 0; i < 2; ++i)
#pragma unroll
        for (int j = 0; j < 4; ++j) {
            const int col = n0 + j * 16 + ln;
            const float bb = bias[col];
#pragma unroll
            for (int g = 0; g < 4; ++g) {
                const int token = m0 + i * 16 + quad * 4 + g;
                C[(size_t)token * DIM_ + col] = acc[i][j][g] + bb;
            }
        }
}

// ---------------------------------------------------------------------------
// MFMA kNN attention. WG = 512 thr (8 waves) = (b,h, 16 q-rows).
// Phase 2 latency-overlap round: both rows' stats reduced in ONE 4-chain
// shuffle loop, both lsum reductions interleaved (2 chains). Searches keep
// the r9 interpolation-seeded exact method (it cut trials 19->~5).
// ---------------------------------------------------------------------------
__global__ __launch_bounds__(512, 4) void attn_mfma(const ushort_t* __restrict__ Qh,
                                                    const ushort_t* __restrict__ Ql,
                                                    const ushort_t* __restrict__ Kh,
                                                    const ushort_t* __restrict__ Kl,
                                                    const ushort_t* __restrict__ Vt,
                                                    ushort_t* __restrict__ Oh,
                                                    ushort_t* __restrict__ Ol) {
    __shared__ float sdots[16 * 1024];        // 64 KB
    __shared__ float spartial[4][16][17];     // 4.25 KB j-split merge buffer

    const int t    = threadIdx.x;
    const int w    = t >> 6;        // wave 0..7
    const int l    = t & 63;
    const int ln   = l & 15;
    const int quad = l >> 4;
    const int wg   = blockIdx.x;
    const int bh   = wg & 31;       // XCD-local heads
    const int i0   = (wg >> 5) << 4;

    const size_t bhoff = (size_t)bh << 16;

    // ---- Q fragments (same for all waves)
    const ushort_t* qp  = Qh + bhoff + (size_t)(i0 + ln) * 64 + (quad << 3);
    const ushort_t* qlp = Ql + bhoff + (size_t)(i0 + ln) * 64 + (quad << 3);
    bf16x8 qh0 = *(const bf16x8*)qp;
    bf16x8 qh1 = *(const bf16x8*)(qp + 32);
    bf16x8 ql0 = *(const bf16x8*)qlp;
    bf16x8 ql1 = *(const bf16x8*)(qlp + 32);

    // ---- Phase 1: dots. wave w covers j in [w*128, w*128+128)
    for (int tt = 0; tt < 8; ++tt) {
        const int j0 = ((w << 3) + tt) << 4;
        const ushort_t* kp  = Kh + bhoff + (size_t)(j0 + ln) * 64 + (quad << 3);
        const ushort_t* klp = Kl + bhoff + (size_t)(j0 + ln) * 64 + (quad << 3);
        bf16x8 kh0 = *(const bf16x8*)kp;
        bf16x8 kh1 = *(const bf16x8*)(kp + 32);
        bf16x8 kl0 = *(const bf16x8*)klp;
        bf16x8 kl1 = *(const bf16x8*)(klp + 32);
        f32x4 acc = {0.f, 0.f, 0.f, 0.f};
        acc = __builtin_amdgcn_mfma_f32_16x16x32_bf16(qh0, kh0, acc, 0, 0, 0);
        acc = __builtin_amdgcn_mfma_f32_16x16x32_bf16(qh1, kh1, acc, 0, 0, 0);
        acc = __builtin_amdgcn_mfma_f32_16x16x32_bf16(qh0, kl0, acc, 0, 0, 0);
        acc = __builtin_amdgcn_mfma_f32_16x16x32_bf16(qh1, kl1, acc, 0, 0, 0);
        acc = __builtin_amdgcn_mfma_f32_16x16x32_bf16(ql0, kh0, acc, 0, 0, 0);
        acc = __builtin_amdgcn_mfma_f32_16x16x32_bf16(ql1, kh1, acc, 0, 0, 0);
#pragma unroll
        for (int g = 0; g < 4; ++g) {
            const int row = (quad << 2) + g;
            sdots[(row << 10) + ((j0 + ln) ^ ((row & 7) << 2))] = acc[g] * SCALE_;
        }
    }
    __syncthreads();

    // ---- Phase 2: fused 2-row top-k + softmax + in-place bf16 P
    ushort_t* sP = (ushort_t*)sdots;
    {
        const int r0 = w << 1, r1 = r0 | 1;
        const int swz0 = (r0 & 7) << 2, swz1 = (r1 & 7) << 2;
        const float* s0 = &sdots[r0 << 10];
        const float* s1 = &sdots[r1 << 10];
        // lane l holds keys for j = 4l + 256m + i  (m=0..3, i=0..3)
        unsigned key0[16], key1[16];
        float sa0 = 0.f, sb0 = 0.f, sa1 = 0.f, sb1 = 0.f;
#pragma unroll
        for (int m = 0; m < 4; ++m) {
            f32x4 kv0 = *(const f32x4*)&s0[((l << 2) + (m << 8)) ^ swz0];
            f32x4 kv1 = *(const f32x4*)&s1[((l << 2) + (m << 8)) ^ swz1];
#pragma unroll
            for (int i = 0; i < 4; ++i) {
                key0[(m << 2) + i] = f2key(kv0[i]);
                key1[(m << 2) + i] = f2key(kv1[i]);
                sa0 += kv0[i];
                sb0 += kv0[i] * kv0[i];
                sa1 += kv1[i];
                sb1 += kv1[i] * kv1[i];
            }
        }
        // 4 independent reduction chains in one loop (latency overlap)
#pragma unroll
        for (int off = 32; off; off >>= 1) {
            sa0 += __shfl_xor(sa0, off, 64);
            sb0 += __shfl_xor(sb0, off, 64);
            sa1 += __shfl_xor(sa1, off, 64);
            sb1 += __shfl_xor(sb1, off, 64);
        }
        const float mu0 = sa0 * (1.0f / 1024.f);
        const float sg0 = sqrtf(fmaxf(sb0 * (1.0f / 1024.f) - mu0 * mu0, 1e-20f));
        const float mu1 = sa1 * (1.0f / 1024.f);
        const float sg1 = sqrtf(fmaxf(sb1 * (1.0f / 1024.f) - mu1 * mu1, 1e-20f));

        const unsigned res0 = topk_thresh(key0, mu0, sg0);
        const unsigned res1 = topk_thresh(key1, mu1, sg1);

        const float thr0 = key2f(res0), thr1 = key2f(res1);
        float pv0[16], pv1[16];
        float ls0 = 0.f, ls1 = 0.f;
#pragma unroll
        for (int m = 0; m < 16; ++m) {
            float p0 = (key0[m] >= res0) ? __expf(key2f(key0[m]) - thr0) : 0.f;
            float p1 = (key1[m] >= res1) ? __expf(key2f(key1[m]) - thr1) : 0.f;
            pv0[m] = p0;
            pv1[m] = p1;
            ls0 += p0;
            ls1 += p1;
        }
#pragma unroll
        for (int off = 32; off; off >>= 1) {
            ls0 += __shfl_xor(ls0, off, 64);
            ls1 += __shfl_xor(ls1, off, 64);
        }
        const float inv0 = 1.f / ls0, inv1 = 1.f / ls1;
        // store P (bf16, phase-3 layout): j = 4l + 256m + i
#pragma unroll
        for (int m = 0; m < 4; ++m) {
            const int g0 = ((l >> 1) + (m << 5)) ^ (r0 & 7);
            const int g1 = ((l >> 1) + (m << 5)) ^ (r1 & 7);
            ushort4 pk0 = make_ushort4(bf16_rne(pv0[(m << 2) + 0] * inv0),
                                       bf16_rne(pv0[(m << 2) + 1] * inv0),
                                       bf16_rne(pv0[(m << 2) + 2] * inv0),
                                       bf16_rne(pv0[(m << 2) + 3] * inv0));
            ushort4 pk1 = make_ushort4(bf16_rne(pv1[(m << 2) + 0] * inv1),
                                       bf16_rne(pv1[(m << 2) + 1] * inv1),
                                       bf16_rne(pv1[(m << 2) + 2] * inv1),
                                       bf16_rne(pv1[(m << 2) + 3] * inv1));
            *(ushort4*)&sP[(r0 << 11) + (g0 << 3) + ((l & 1) << 2)] = pk0;
            *(ushort4*)&sP[(r1 << 11) + (g1 << 3) + ((l & 1) << 2)] = pk1;
        }
    }
    __syncthreads();

    // ---- Phase 3: O = P @ V.  wave w: d-block (w&3), j-half (w&4 ? hi : lo)
    const int dblk  = w & 3;
    const int jbase = (w & 4) << 7;   // 0 or 512
    f32x4 oacc = {0.f, 0.f, 0.f, 0.f};
    const ushort_t* vp =
        Vt + bhoff + (size_t)((dblk << 4) + ln) * 1024 + (quad << 3) + jbase;
    const int prow = ln << 11;
    const int rsw  = ln & 7;
#pragma unroll
    for (int j0 = 0; j0 < 512; j0 += 32) {
        const int g = ((jbase + j0) >> 3) + quad;
        bf16x8 af = *(const bf16x8*)&sP[prow + ((g ^ rsw) << 3)];
        bf16x8 bv = *(const bf16x8*)(vp + j0);
        oacc = __builtin_amdgcn_mfma_f32_16x16x32_bf16(af, bv, oacc, 0, 0, 0);
    }
    if (w & 4) {
#pragma unroll
        for (int g = 0; g < 4; ++g)
            spartial[dblk][(quad << 2) + g][ln] = oacc[g];
    }
    __syncthreads();
    if (!(w & 4)) {
        const int b = bh >> 3, h = bh & 7;
        const size_t obase =
            ((size_t)(b << 10) + i0 + (quad << 2)) * 512 + (h << 6) + (dblk << 4) + ln;
#pragma unroll
        for (int g = 0; g < 4; ++g) {
            const float v = oacc[g] + spartial[dblk][(quad << 2) + g][ln];
            ushort_t hb = bf16_rne(v);
            Oh[obase + (size_t)g * 512] = hb;
            Ol[obase + (size_t)g * 512] = bf16_rne(v - bf16_f(hb));
        }
    }
}

extern "C" void kernel_launch(void* const* d_in, const int* in_sizes, int n_in,
                              void* d_out, int out_size, void* d_ws, size_t ws_size,
                              hipStream_t stream) {
    const float* x     = (const float*)d_in[0];
    const float* w_qkv = (const float*)d_in[1];
    const float* w_out = (const float*)d_in[2];
    const float* b_out = (const float*)d_in[3];
    float*       out   = (float*)d_out;

    const size_t ON  = (size_t)4096 * 512;
    const size_t WQT = (size_t)1536 * 512;
    const size_t WOT = (size_t)512 * 512;
    const size_t QK  = (size_t)32 * 1024 * 64;

    ushort_t* p    = (ushort_t*)d_ws;
    ushort_t* Oh   = p;            p += ON;
    ushort_t* Ol   = p;            p += ON;
    ushort_t* WqTh = p;            p += WQT;
    ushort_t* WqTl = p;            p += WQT;
    ushort_t* WoTh = p;            p += WOT;
    ushort_t* WoTl = p;            p += WOT;
    ushort_t* Qh   = p;            p += QK;
    ushort_t* Ql   = p;            p += QK;
    ushort_t* Kh   = p;            p += QK;
    ushort_t* Kl   = p;            p += QK;
    ushort_t* Vt   = p;            p += QK;   // total exactly 32 MiB

    conv_wT2<<<dim3(64, 16), 256, 0, stream>>>(w_qkv, w_out, WqTh, WqTl, WoTh, WoTl);

    // blockIdx.x = m-block so A tiles are XCD-local
    gemm_qkv_mfma<<<dim3(4096 / 128, TRIPLE_ / 64), 256, 0, stream>>>(
        x, WqTh, WqTl, Qh, Ql, Kh, Kl, Vt);

    attn_mfma<<<dim3(B_ * H_ * (N_ / 16)), 512, 0, stream>>>(Qh, Ql, Kh, Kl, Vt, Oh, Ol);

    gemm_out_mfma<<<dim3(4096 / 128, DIM_ / 64), 256, 0, stream>>>(
        Oh, Ol, WoTh, WoTl, b_out, out);
}